// Round 5
// baseline (42.248 us; speedup 1.0000x reference)
//
#include <hip/hip_runtime.h>

// Problem constants (from reference)
#define N_ATOMS   500000
#define N_ALT     4
#define NB        2      // N_BATCH
#define NC        4      // N_CHAIN
#define NR        50000  // N_RES
#define SG_HASH   16
#define TEMP      298.0f

// Output layout (flat float32):
//   [0, 1600000)            residueEnergy (2,4,50000,4)
//   [1600000, 3600000)      atomEnergy    (500000,4)
//   [3600000, 3600000+P)    sulfur        (P,) as 0.0/1.0
#define RESE_SIZE  (NB * NC * NR * N_ALT)   // 1,600,000
#define ATOME_SIZE (N_ATOMS * N_ALT)        // 2,000,000
#define ZERO_F4    ((RESE_SIZE + ATOME_SIZE) / 4)   // 900,000 float4 stores

#define MASK_W64   ((N_ATOMS + 63) / 64)    // 7813 u64 = 62,504 B
#define MASK_W32   (MASK_W64 * 2)           // 15626 u32

// Native clang vector types — required by __builtin_nontemporal_load/store
// (HIP_vector_type int4/float4 are structs and are rejected).
typedef int   intx4 __attribute__((ext_vector_type(4)));
typedef float fltx4 __attribute__((ext_vector_type(4)));

// ---------------------------------------------------------------------------
// Kernel A (prep): zero resE+atomE with float4 stores AND build the packed
// SG bitmask via __ballot — one launch, streaming-BW zeroing (the rocclr
// fillBuffer kernel ran at 353 GB/s / 8.5% occupancy: grid-limited).
// ---------------------------------------------------------------------------
__global__ __launch_bounds__(1024) void prep_kernel(
    const int* __restrict__ adesc,              // (N,4)
    float* __restrict__ zero_base,              // resE (zero 3.6M floats)
    unsigned long long* __restrict__ mask)      // (MASK_W64,)
{
    int i = blockIdx.x * 1024 + threadIdx.x;

    if (i < ZERO_F4) {
        fltx4 z = {0.f, 0.f, 0.f, 0.f};
        reinterpret_cast<fltx4*>(zero_base)[i] = z;
    }

    bool s = false;
    if (i < N_ATOMS) s = (adesc[(size_t)i * 4 + 3] == SG_HASH);
    unsigned long long b = __ballot(s);
    if (i < N_ATOMS && (threadIdx.x & 63) == 0) mask[i >> 6] = b;
}

// ---------------------------------------------------------------------------
// Cold path: full energy + scatter for a sulfur pair (~0.1% of pairs).
// ---------------------------------------------------------------------------
__device__ __forceinline__ void heavy_pair(
    int p0, int p1,
    const float* __restrict__ coords,
    const int*   __restrict__ adesc,
    const int*   __restrict__ altmask,
    float* __restrict__ resE,
    float* __restrict__ atomE)
{
    int4 d0 = *reinterpret_cast<const int4*>(adesc + (size_t)p0 * 4);
    int4 d1 = *reinterpret_cast<const int4*>(adesc + (size_t)p1 * 4);

    float dx = coords[(size_t)p0 * 3 + 0] - coords[(size_t)p1 * 3 + 0] + 1e-6f;
    float dy = coords[(size_t)p0 * 3 + 1] - coords[(size_t)p1 * 3 + 1] + 1e-6f;
    float dz = coords[(size_t)p0 * 3 + 2] - coords[(size_t)p1 * 3 + 2] + 1e-6f;
    float dist = sqrtf(dx * dx + dy * dy + dz * dz);

    float rd = fabsf((float)(d0.z - d1.z));      // sulfur => rd >= 1, log safe
    float energy = -0.001f * TEMP * (2.1f + 2.9823825f * logf(rd))
                 + 5.0f * fabsf(dist - 2.04f);
    float netE = 0.5f * energy;

    int4 m0 = *reinterpret_cast<const int4*>(altmask + (size_t)p0 * 4);
    int4 m1 = *reinterpret_cast<const int4*>(altmask + (size_t)p1 * 4);

    int f0 = ((d0.x * NC + d0.y) * NR + d0.z) * N_ALT;
    int f1 = ((d1.x * NC + d1.y) * NR + d1.z) * N_ALT;

    const int* m0p = &m0.x;
    const int* m1p = &m1.x;
#pragma unroll
    for (int a = 0; a < N_ALT; ++a) {
        if (m0p[a] & m1p[a]) {
            atomicAdd(atomE + (size_t)p0 * N_ALT + a, netE);
            atomicAdd(atomE + (size_t)p1 * N_ALT + a, netE);
            atomicAdd(resE + f0 + a, netE);
            atomicAdd(resE + f1 + a, netE);
        }
    }
}

__device__ __forceinline__ bool probe2(const unsigned int* __restrict__ lm,
                                       int a, int b) {
    unsigned m = (lm[a >> 5] >> (a & 31)) & (lm[b >> 5] >> (b & 31));
    return m & 1u;
}

// ---------------------------------------------------------------------------
// Kernel B: broadcast the 62.5 KB SG bitmask into LDS, then grid-stride over
// pairs, 8 pairs/thread/iter (4x int4 loads in flight). Nontemporal hints on
// the touch-once pair stream and sulfur stores keep L2 for the mask/gathers.
// 1024-thread blocks, 62.5 KB LDS -> 2 blocks/CU = 32 waves/CU (100% occ).
// ---------------------------------------------------------------------------
__global__ __launch_bounds__(1024) void disulfide_pair_kernel(
    const float* __restrict__ coords,
    const int*   __restrict__ adesc,    // (N,4)
    const int*   __restrict__ pairs,    // (P,2)
    const int*   __restrict__ altmask,  // (N,4) 0/1
    const unsigned int* __restrict__ sgmask32,
    float* __restrict__ resE,
    float* __restrict__ atomE,
    float* __restrict__ sulfur,
    int P)
{
    __shared__ unsigned int lmask[MASK_W32];   // 62,504 B

    for (int w = threadIdx.x; w < MASK_W32; w += 1024)
        lmask[w] = sgmask32[w];
    __syncthreads();

    const int tid    = blockIdx.x * 1024 + threadIdx.x;
    const int stride = gridDim.x * 1024 * 8;

    for (int i0 = tid * 8; i0 < P; i0 += stride) {
        const intx4* pp = reinterpret_cast<const intx4*>(pairs + (size_t)i0 * 2);
        intx4 pa = __builtin_nontemporal_load(pp + 0);   // pairs i0, i0+1
        intx4 pb = __builtin_nontemporal_load(pp + 1);   // pairs i0+2, i0+3
        intx4 pc = __builtin_nontemporal_load(pp + 2);   // pairs i0+4, i0+5
        intx4 pd = __builtin_nontemporal_load(pp + 3);   // pairs i0+6, i0+7

        bool s0 = probe2(lmask, pa.x, pa.y);
        bool s1 = probe2(lmask, pa.z, pa.w);
        bool s2 = probe2(lmask, pb.x, pb.y);
        bool s3 = probe2(lmask, pb.z, pb.w);
        bool s4 = probe2(lmask, pc.x, pc.y);
        bool s5 = probe2(lmask, pc.z, pc.w);
        bool s6 = probe2(lmask, pd.x, pd.y);
        bool s7 = probe2(lmask, pd.z, pd.w);

        fltx4 sv0 = {s0 ? 1.0f : 0.0f, s1 ? 1.0f : 0.0f,
                     s2 ? 1.0f : 0.0f, s3 ? 1.0f : 0.0f};
        fltx4 sv1 = {s4 ? 1.0f : 0.0f, s5 ? 1.0f : 0.0f,
                     s6 ? 1.0f : 0.0f, s7 ? 1.0f : 0.0f};
        fltx4* sp = reinterpret_cast<fltx4*>(sulfur + i0);
        __builtin_nontemporal_store(sv0, sp + 0);
        __builtin_nontemporal_store(sv1, sp + 1);

        if (s0) heavy_pair(pa.x, pa.y, coords, adesc, altmask, resE, atomE);
        if (s1) heavy_pair(pa.z, pa.w, coords, adesc, altmask, resE, atomE);
        if (s2) heavy_pair(pb.x, pb.y, coords, adesc, altmask, resE, atomE);
        if (s3) heavy_pair(pb.z, pb.w, coords, adesc, altmask, resE, atomE);
        if (s4) heavy_pair(pc.x, pc.y, coords, adesc, altmask, resE, atomE);
        if (s5) heavy_pair(pc.z, pc.w, coords, adesc, altmask, resE, atomE);
        if (s6) heavy_pair(pd.x, pd.y, coords, adesc, altmask, resE, atomE);
        if (s7) heavy_pair(pd.z, pd.w, coords, adesc, altmask, resE, atomE);
    }
}

extern "C" void kernel_launch(void* const* d_in, const int* in_sizes, int n_in,
                              void* d_out, int out_size, void* d_ws, size_t ws_size,
                              hipStream_t stream) {
    const float* coords  = (const float*)d_in[0];
    const int*   adesc   = (const int*)d_in[1];
    // d_in[2] = atom_number (unused)
    const int*   pairs   = (const int*)d_in[3];
    const int*   altmask = (const int*)d_in[4];
    // d_in[5] = partners (unused), d_in[6] = facc (unused)

    const int P = in_sizes[3] / 2;   // 8,000,000

    float* out    = (float*)d_out;
    float* resE   = out;
    float* atomE  = out + RESE_SIZE;
    float* sulfur = out + RESE_SIZE + ATOME_SIZE;

    unsigned long long* sgmask = (unsigned long long*)d_ws;   // 62.5 KB

    // Kernel A: zero accumulated outputs + build SG bitmask (one launch).
    {
        const int threads = 1024;
        const int blocks  = (ZERO_F4 + threads - 1) / threads;   // 879
        prep_kernel<<<blocks, threads, 0, stream>>>(adesc, resE, sgmask);
    }

    // Kernel B: pair streaming with LDS-resident bitmask.
    {
        const int threads = 1024;
        const int blocks  = 512;     // 2 resident blocks/CU on 256 CUs
        disulfide_pair_kernel<<<blocks, threads, 0, stream>>>(
            coords, adesc, pairs, altmask, (const unsigned int*)sgmask,
            resE, atomE, sulfur, P);
    }
}

// Round 6
// 29.390 us; speedup vs baseline: 1.4375x; 1.4375x over previous
//
#include <hip/hip_runtime.h>

// Problem constants (from reference)
#define N_ATOMS   500000
#define N_ALT     4
#define NB        2      // N_BATCH
#define NC        4      // N_CHAIN
#define NR        50000  // N_RES
#define SG_HASH   16
#define TEMP      298.0f

// Output layout (flat float32):
//   [0, 1600000)            residueEnergy (2,4,50000,4)
//   [1600000, 3600000)      atomEnergy    (500000,4)
//   [3600000, 3600000+P)    sulfur        (P,) as 0.0/1.0
#define RESE_SIZE  (NB * NC * NR * N_ALT)   // 1,600,000
#define ATOME_SIZE (N_ATOMS * N_ALT)        // 2,000,000
#define ZERO_F4    ((RESE_SIZE + ATOME_SIZE) / 4)   // 900,000 float4 stores

#define MASK_W64   ((N_ATOMS + 63) / 64)    // 7813 u64 = 62,504 B
#define MASK_W32   (MASK_W64 * 2)           // 15626 u32

// ---------------------------------------------------------------------------
// Kernel A (prep): zero resE+atomE with float4 stores AND build the packed
// SG bitmask via __ballot — one launch. (The rocclr fillBuffer kernel was
// grid-limited; fused streaming zeroing is strictly cheaper.)
// ---------------------------------------------------------------------------
__global__ __launch_bounds__(1024) void prep_kernel(
    const int* __restrict__ adesc,              // (N,4)
    float* __restrict__ zero_base,              // resE (zero 3.6M floats)
    unsigned long long* __restrict__ mask)      // (MASK_W64,)
{
    int i = blockIdx.x * 1024 + threadIdx.x;

    if (i < ZERO_F4)
        reinterpret_cast<float4*>(zero_base)[i] = make_float4(0.f, 0.f, 0.f, 0.f);

    bool s = false;
    if (i < N_ATOMS) s = (adesc[(size_t)i * 4 + 3] == SG_HASH);
    unsigned long long b = __ballot(s);
    if (i < N_ATOMS && (threadIdx.x & 63) == 0) mask[i >> 6] = b;
}

// ---------------------------------------------------------------------------
// Cold path: full energy + scatter for a sulfur pair (~0.1% of pairs).
// ---------------------------------------------------------------------------
__device__ __forceinline__ void heavy_pair(
    int p0, int p1,
    const float* __restrict__ coords,
    const int*   __restrict__ adesc,
    const int*   __restrict__ altmask,
    float* __restrict__ resE,
    float* __restrict__ atomE)
{
    int4 d0 = *reinterpret_cast<const int4*>(adesc + (size_t)p0 * 4);
    int4 d1 = *reinterpret_cast<const int4*>(adesc + (size_t)p1 * 4);

    float dx = coords[(size_t)p0 * 3 + 0] - coords[(size_t)p1 * 3 + 0] + 1e-6f;
    float dy = coords[(size_t)p0 * 3 + 1] - coords[(size_t)p1 * 3 + 1] + 1e-6f;
    float dz = coords[(size_t)p0 * 3 + 2] - coords[(size_t)p1 * 3 + 2] + 1e-6f;
    float dist = sqrtf(dx * dx + dy * dy + dz * dz);

    float rd = fabsf((float)(d0.z - d1.z));      // sulfur => rd >= 1, log safe
    float energy = -0.001f * TEMP * (2.1f + 2.9823825f * logf(rd))
                 + 5.0f * fabsf(dist - 2.04f);
    float netE = 0.5f * energy;

    int4 m0 = *reinterpret_cast<const int4*>(altmask + (size_t)p0 * 4);
    int4 m1 = *reinterpret_cast<const int4*>(altmask + (size_t)p1 * 4);

    int f0 = ((d0.x * NC + d0.y) * NR + d0.z) * N_ALT;
    int f1 = ((d1.x * NC + d1.y) * NR + d1.z) * N_ALT;

    const int* m0p = &m0.x;
    const int* m1p = &m1.x;
#pragma unroll
    for (int a = 0; a < N_ALT; ++a) {
        if (m0p[a] & m1p[a]) {
            atomicAdd(atomE + (size_t)p0 * N_ALT + a, netE);
            atomicAdd(atomE + (size_t)p1 * N_ALT + a, netE);
            atomicAdd(resE + f0 + a, netE);
            atomicAdd(resE + f1 + a, netE);
        }
    }
}

__device__ __forceinline__ bool probe2(const unsigned int* __restrict__ lm,
                                       int a, int b) {
    unsigned m = (lm[a >> 5] >> (a & 31)) & (lm[b >> 5] >> (b & 31));
    return m & 1u;
}

// ---------------------------------------------------------------------------
// Kernel B: broadcast the 62.5 KB SG bitmask into LDS, then grid-stride over
// pairs, 8 pairs/thread/iter (4x int4 loads in flight). Plain (cached) loads:
// the pair stream is L3-resident across replays (round-2 FETCH evidence) —
// nontemporal hints forfeited that and regressed (round 5).
// 1024-thread blocks, 62.5 KB LDS -> 2 blocks/CU = 32 waves/CU (100% occ).
// ---------------------------------------------------------------------------
__global__ __launch_bounds__(1024) void disulfide_pair_kernel(
    const float* __restrict__ coords,
    const int*   __restrict__ adesc,    // (N,4)
    const int*   __restrict__ pairs,    // (P,2)
    const int*   __restrict__ altmask,  // (N,4) 0/1
    const unsigned int* __restrict__ sgmask32,
    float* __restrict__ resE,
    float* __restrict__ atomE,
    float* __restrict__ sulfur,
    int P)
{
    __shared__ unsigned int lmask[MASK_W32];   // 62,504 B

    for (int w = threadIdx.x; w < MASK_W32; w += 1024)
        lmask[w] = sgmask32[w];
    __syncthreads();

    const int tid    = blockIdx.x * 1024 + threadIdx.x;
    const int stride = gridDim.x * 1024 * 8;

    for (int i0 = tid * 8; i0 < P; i0 += stride) {
        const int4* pp = reinterpret_cast<const int4*>(pairs + (size_t)i0 * 2);
        int4 pa = pp[0];   // pairs i0, i0+1
        int4 pb = pp[1];   // pairs i0+2, i0+3
        int4 pc = pp[2];   // pairs i0+4, i0+5
        int4 pd = pp[3];   // pairs i0+6, i0+7

        bool s0 = probe2(lmask, pa.x, pa.y);
        bool s1 = probe2(lmask, pa.z, pa.w);
        bool s2 = probe2(lmask, pb.x, pb.y);
        bool s3 = probe2(lmask, pb.z, pb.w);
        bool s4 = probe2(lmask, pc.x, pc.y);
        bool s5 = probe2(lmask, pc.z, pc.w);
        bool s6 = probe2(lmask, pd.x, pd.y);
        bool s7 = probe2(lmask, pd.z, pd.w);

        float4 sv0 = make_float4(s0 ? 1.0f : 0.0f, s1 ? 1.0f : 0.0f,
                                 s2 ? 1.0f : 0.0f, s3 ? 1.0f : 0.0f);
        float4 sv1 = make_float4(s4 ? 1.0f : 0.0f, s5 ? 1.0f : 0.0f,
                                 s6 ? 1.0f : 0.0f, s7 ? 1.0f : 0.0f);
        float4* sp = reinterpret_cast<float4*>(sulfur + i0);
        sp[0] = sv0;
        sp[1] = sv1;

        if (s0) heavy_pair(pa.x, pa.y, coords, adesc, altmask, resE, atomE);
        if (s1) heavy_pair(pa.z, pa.w, coords, adesc, altmask, resE, atomE);
        if (s2) heavy_pair(pb.x, pb.y, coords, adesc, altmask, resE, atomE);
        if (s3) heavy_pair(pb.z, pb.w, coords, adesc, altmask, resE, atomE);
        if (s4) heavy_pair(pc.x, pc.y, coords, adesc, altmask, resE, atomE);
        if (s5) heavy_pair(pc.z, pc.w, coords, adesc, altmask, resE, atomE);
        if (s6) heavy_pair(pd.x, pd.y, coords, adesc, altmask, resE, atomE);
        if (s7) heavy_pair(pd.z, pd.w, coords, adesc, altmask, resE, atomE);
    }
}

extern "C" void kernel_launch(void* const* d_in, const int* in_sizes, int n_in,
                              void* d_out, int out_size, void* d_ws, size_t ws_size,
                              hipStream_t stream) {
    const float* coords  = (const float*)d_in[0];
    const int*   adesc   = (const int*)d_in[1];
    // d_in[2] = atom_number (unused)
    const int*   pairs   = (const int*)d_in[3];
    const int*   altmask = (const int*)d_in[4];
    // d_in[5] = partners (unused), d_in[6] = facc (unused)

    const int P = in_sizes[3] / 2;   // 8,000,000

    float* out    = (float*)d_out;
    float* resE   = out;
    float* atomE  = out + RESE_SIZE;
    float* sulfur = out + RESE_SIZE + ATOME_SIZE;

    unsigned long long* sgmask = (unsigned long long*)d_ws;   // 62.5 KB

    // Kernel A: zero accumulated outputs + build SG bitmask (one launch).
    {
        const int threads = 1024;
        const int blocks  = (ZERO_F4 + threads - 1) / threads;   // 879
        prep_kernel<<<blocks, threads, 0, stream>>>(adesc, resE, sgmask);
    }

    // Kernel B: pair streaming with LDS-resident bitmask.
    {
        const int threads = 1024;
        const int blocks  = 512;     // 2 resident blocks/CU on 256 CUs
        disulfide_pair_kernel<<<blocks, threads, 0, stream>>>(
            coords, adesc, pairs, altmask, (const unsigned int*)sgmask,
            resE, atomE, sulfur, P);
    }
}